// Round 6
// baseline (101.606 us; speedup 1.0000x reference)
//
#include <hip/hip_runtime.h>
#include <cstdint>
#include <cstddef>

typedef _Float16 f16;
typedef f16 f16x8 __attribute__((ext_vector_type(8)));
typedef f16 f16x4 __attribute__((ext_vector_type(4)));
typedef float floatx4 __attribute__((ext_vector_type(4)));

#define GAS __attribute__((address_space(1)))
#define LAS __attribute__((address_space(3)))

static constexpr int LSEQ = 2048;
static constexpr int NH   = 8;
static constexpr int DH   = 64;
static constexpr int DM   = 512;
static constexpr int WIN  = 64;
static constexpr int MR   = 4 * LSEQ;  // 8192 rows (B*L)

// ------------------------------------------- prep: cast x->f16  +  transpose W->f16
__global__ __launch_bounds__(256) void prep_kernel(
    const float* __restrict__ x, f16* __restrict__ xb,
    const float* __restrict__ Wq, const float* __restrict__ Wk,
    const float* __restrict__ Wv, const float* __restrict__ Wo,
    f16* __restrict__ wt) {
    __shared__ float tile[32][33];
    int bid = blockIdx.x;
    if (bid < 4096) {
        int i = bid * 256 + threadIdx.x;      // 4 elements/thread
        float4 v = ((const float4*)x)[i];
        f16x4 o = { (f16)v.x, (f16)v.y, (f16)v.z, (f16)v.w };
        ((f16x4*)xb)[i] = o;
    } else {
        int id = bid - 4096;
        int z  = id >> 8, t = id & 255;
        const float* W = z == 0 ? Wq : z == 1 ? Wk : z == 2 ? Wv : Wo;
        f16* out = wt + (size_t)z * DM * DM;
        int c0 = (t & 15) * 32, r0 = (t >> 4) * 32;
        int tx = threadIdx.x & 31, ty = threadIdx.x >> 5;
        #pragma unroll
        for (int i = 0; i < 32; i += 8)
            tile[ty + i][tx] = W[(size_t)(r0 + ty + i) * DM + c0 + tx];
        __syncthreads();
        #pragma unroll
        for (int i = 0; i < 32; i += 8)
            out[(size_t)(c0 + ty + i) * DM + r0 + tx] = (f16)tile[tx][ty + i];
    }
}

// ------------------------------------------------- GEMM: direct-load, barrier-free
// Block = 4 waves; wave w computes rows [m0+w*64, +64) x cols [n0, n0+64).
// B-panel (64 cols x K=512 = 64KB) staged to LDS ONCE (single drain, amortized);
// K-loop reads A directly from global (plain loads -> compiler pipelines freely),
// B from LDS. NO barriers in the K-loop. XOR swizzle g^(col&7) both sides (#21).
// Decode (chunked XCD swizzle): lin=(hw&7)*chunk+hw/8; n0=(lin&7)*64,
// m0=((lin>>3)&31)*256, z=lin>>8.
template <bool QKV>
__global__ __launch_bounds__(256) void gemm_kernel(
    const f16* __restrict__ A, const f16* __restrict__ Bt_base,
    const float* __restrict__ b0, const float* __restrict__ b1,
    const float* __restrict__ b2,
    f16* __restrict__ out_q, f16* __restrict__ out_k, f16* __restrict__ out_vt,
    float* __restrict__ out_f) {
    const int chunk = gridDim.x >> 3;
    const int hw  = blockIdx.x;
    const int lin = (hw & 7) * chunk + (hw >> 3);
    const int n0  = (lin & 7) * 64;
    const int m0  = ((lin >> 3) & 31) * 256;
    const int z   = QKV ? (lin >> 8) : 0;

    const f16* __restrict__ Bt = Bt_base + (size_t)z * (DM * DM);
    const float* __restrict__ bias = QKV ? (z == 0 ? b0 : z == 1 ? b1 : b2) : b0;

    __shared__ f16 Bs[64 * 512];   // 64 KB: [col][g_phys*8], g_phys = g ^ (col&7)

    const int tid  = threadIdx.x;
    const int wid  = tid >> 6;
    const int lane = tid & 63;
    const int l15  = lane & 15;
    const int l4   = lane >> 4;
    const int rbase = m0 + wid * 64;

    // ---- stage B panel: 4096 16B-granules; lds slot gg=(col,g') linear in gg,
    // global source granule = g' ^ (col&7)  (XOR involution, rule #21)
    #pragma unroll
    for (int i = 0; i < 16; ++i) {
        int gg  = i * 256 + tid;
        int col = gg >> 6, gp = gg & 63;
        int sg  = gp ^ (col & 7);
        const f16* g = Bt + (size_t)(n0 + col) * DM + sg * 8;
        f16* l = &Bs[(i * 256 + wid * 64) * 8];   // +lane*16B by HW
        __builtin_amdgcn_global_load_lds((const GAS void*)g, (LAS void*)l, 16, 0, 0);
    }
    __syncthreads();   // one drain for the whole kernel

    floatx4 acc[4][4] = {};

    #pragma unroll 4
    for (int ks = 0; ks < 16; ++ks) {
        f16x8 af[4], bfr[4];
        #pragma unroll
        for (int m = 0; m < 4; ++m)
            af[m] = *(const f16x8*)(A + (size_t)(rbase + m * 16 + l15) * DM + ks * 32 + l4 * 8);
        #pragma unroll
        for (int n = 0; n < 4; ++n) {
            int col = n * 16 + l15;
            int gp  = (ks * 4 + l4) ^ (col & 7);
            bfr[n] = *(const f16x8*)(&Bs[col * 512 + gp * 8]);
        }
        #pragma unroll
        for (int m = 0; m < 4; ++m)
            #pragma unroll
            for (int n = 0; n < 4; ++n)
                acc[m][n] = __builtin_amdgcn_mfma_f32_16x16x32_f16(af[m], bfr[n], acc[m][n], 0, 0, 0);
    }

    // epilogue; D layout: col = lane&15, row = (lane>>4)*4 + r  (m89-verified)
    #pragma unroll
    for (int n = 0; n < 4; ++n) {
        int gcol = n0 + n * 16 + l15;
        float bias_v = bias[gcol];
        #pragma unroll
        for (int m = 0; m < 4; ++m) {
            int grow0 = rbase + m * 16 + l4 * 4;
            #pragma unroll
            for (int r = 0; r < 4; ++r) {
                int grow = grow0 + r;
                float v = acc[m][n][r] + bias_v;
                if constexpr (QKV) {
                    int b = grow >> 11, lp = grow & (LSEQ - 1);
                    int h = gcol >> 6,  d  = gcol & (DH - 1);
                    int bh = b * NH + h;
                    if (z == 0)       // Q, pre-scaled by 1/sqrt(Dh) (exact pow2)
                        out_q[((size_t)bh * LSEQ + lp) * DH + d] = (f16)(v * 0.125f);
                    else if (z == 1)  // K: [bh][l][d]
                        out_k[((size_t)bh * LSEQ + lp) * DH + d] = (f16)v;
                    else              // V transposed: [bh][d][l]
                        out_vt[((size_t)bh * DH + d) * LSEQ + lp] = (f16)v;
                } else {
                    out_f[(size_t)grow * DM + gcol] = v;
                }
            }
        }
    }
}

// ---------------------------------------------------------------- windowed attention
// 1-D grid 1024 + chunked-XCD swizzle (4 heads' K/V per XCD -> L2-resident).
// block: (64 queries of one bh), 4 waves x 16 queries; key window = 192 wide
__global__ __launch_bounds__(256) void attn_kernel(const f16* __restrict__ Qb,
                                                   const f16* __restrict__ Kb,
                                                   const f16* __restrict__ Vt,
                                                   f16* __restrict__ Ob) {
    const int hw  = blockIdx.x;
    const int lin = (hw & 7) * 128 + (hw >> 3);
    const int bh    = lin >> 5;
    const int q0blk = (lin & 31) * 64;
    const int wid    = threadIdx.x >> 6;
    const int lane   = threadIdx.x & 63;
    const int l15    = lane & 15, l4 = lane >> 4;
    const int qbase  = q0blk + wid * 16;
    const int kstart = q0blk - WIN;

    const f16* __restrict__ Q = Qb + (size_t)bh * LSEQ * DH;
    const f16* __restrict__ K = Kb + (size_t)bh * LSEQ * DH;
    const f16* __restrict__ V = Vt + (size_t)bh * DH * LSEQ;

    __shared__ f16 Pl[4][16][232];   // 464B row stride: 16B-aligned, bank-spread

    // Q fragments (A operand): row = l15, k = ks*32 + l4*8 + i
    f16x8 qf[2];
    #pragma unroll
    for (int ks = 0; ks < 2; ++ks)
        qf[ks] = *(const f16x8*)(Q + (size_t)(qbase + l15) * DH + ks * 32 + l4 * 8);

    // S = Q K^T : 12 n-tiles of 16 keys
    floatx4 sc[12] = {};
    #pragma unroll
    for (int nt = 0; nt < 12; ++nt) {
        int key = kstart + nt * 16 + l15;
        int kcl = key < 0 ? 0 : (key > LSEQ - 1 ? LSEQ - 1 : key);
        #pragma unroll
        for (int ks = 0; ks < 2; ++ks) {
            f16x8 kf = *(const f16x8*)(K + (size_t)kcl * DH + ks * 32 + l4 * 8);
            sc[nt] = __builtin_amdgcn_mfma_f32_16x16x32_f16(qf[ks], kf, sc[nt], 0, 0, 0);
        }
    }

    // mask + softmax. Row q = qbase + l4*4 + r lives in the 16 lanes sharing l4.
    float mx[4] = {-1e30f, -1e30f, -1e30f, -1e30f};
    #pragma unroll
    for (int nt = 0; nt < 12; ++nt) {
        int key = kstart + nt * 16 + l15;
        #pragma unroll
        for (int r = 0; r < 4; ++r) {
            int q = qbase + l4 * 4 + r;
            int dist = key - q; dist = dist < 0 ? -dist : dist;
            bool valid = (key >= 0) && (key < LSEQ) && (dist <= WIN);
            float s = valid ? sc[nt][r] : -1e30f;
            sc[nt][r] = s;
            mx[r] = fmaxf(mx[r], s);
        }
    }
    #pragma unroll
    for (int r = 0; r < 4; ++r)
        #pragma unroll
        for (int m = 1; m < 16; m <<= 1)
            mx[r] = fmaxf(mx[r], __shfl_xor(mx[r], m, 64));
    float sm[4] = {0.f, 0.f, 0.f, 0.f};
    #pragma unroll
    for (int nt = 0; nt < 12; ++nt)
        #pragma unroll
        for (int r = 0; r < 4; ++r) {
            float p = __expf(sc[nt][r] - mx[r]);
            sc[nt][r] = p;
            sm[r] += p;
        }
    #pragma unroll
    for (int r = 0; r < 4; ++r) {
        #pragma unroll
        for (int m = 1; m < 16; m <<= 1)
            sm[r] += __shfl_xor(sm[r], m, 64);
        sm[r] = 1.f / sm[r];
    }

    // P -> LDS in A-fragment-friendly layout
    #pragma unroll
    for (int nt = 0; nt < 12; ++nt)
        #pragma unroll
        for (int r = 0; r < 4; ++r)
            Pl[wid][l4 * 4 + r][nt * 16 + l15] = (f16)(sc[nt][r] * sm[r]);
    __syncthreads();

    // O = P V : A-frag from LDS (contiguous), B-frag from Vt (contiguous keys)
    floatx4 oc[4] = {};
    #pragma unroll
    for (int ks = 0; ks < 6; ++ks) {
        f16x8 pf = *(const f16x8*)(&Pl[wid][l15][ks * 32 + l4 * 8]);
        int kb0 = kstart + ks * 32 + l4 * 8;
        int kbc = (kb0 < 0 || kb0 > LSEQ - 8) ? 0 : kb0;  // whole chunk valid or P==0
        #pragma unroll
        for (int dt = 0; dt < 4; ++dt) {
            f16x8 vf = *(const f16x8*)(V + (size_t)(dt * 16 + l15) * LSEQ + kbc);
            oc[dt] = __builtin_amdgcn_mfma_f32_16x16x32_f16(pf, vf, oc[dt], 0, 0, 0);
        }
    }

    // write O in [B][L][H*64] f16 (A operand of final GEMM)
    int b = bh >> 3, h = bh & 7;
    #pragma unroll
    for (int dt = 0; dt < 4; ++dt) {
        int d = dt * 16 + l15;
        #pragma unroll
        for (int r = 0; r < 4; ++r) {
            int q = qbase + l4 * 4 + r;
            Ob[((size_t)b * LSEQ + q) * DM + h * DH + d] = (f16)oc[dt][r];
        }
    }
}

// ---------------------------------------------------------------- launch
extern "C" void kernel_launch(void* const* d_in, const int* in_sizes, int n_in,
                              void* d_out, int out_size, void* d_ws, size_t ws_size,
                              hipStream_t stream) {
    const float* x  = (const float*)d_in[0];
    const float* Wq = (const float*)d_in[1];
    const float* bq = (const float*)d_in[2];
    const float* Wk = (const float*)d_in[3];
    const float* bk = (const float*)d_in[4];
    const float* Wv = (const float*)d_in[5];
    const float* bv = (const float*)d_in[6];
    const float* Wo = (const float*)d_in[7];
    const float* bo = (const float*)d_in[8];
    float* out = (float*)d_out;

    char* ws = (char*)d_ws;
    f16* xb = (f16*)(ws);                       // 8 MB  [8192][512]
    f16* wt = (f16*)(ws + (8ull << 20));        // 2 MB  WqT,WkT,WvT,WoT
    f16* qb = (f16*)(ws + (10ull << 20));       // 8 MB  [32][2048][64], pre-scaled
    f16* kb = (f16*)(ws + (18ull << 20));       // 8 MB  [32][2048][64]
    f16* vt = (f16*)(ws + (26ull << 20));       // 8 MB  [32][64][2048]
    f16* ob = (f16*)(ws + (34ull << 20));       // 8 MB  [8192][512]

    prep_kernel<<<dim3(5120), 256, 0, stream>>>(x, xb, Wq, Wk, Wv, Wo, wt);
    gemm_kernel<true><<<dim3(768), 256, 0, stream>>>(
        xb, wt, bq, bk, bv, qb, kb, vt, nullptr);
    attn_kernel<<<dim3(1024), 256, 0, stream>>>(qb, kb, vt, ob);
    gemm_kernel<false><<<dim3(256), 256, 0, stream>>>(
        ob, wt + 3ull * DM * DM, bo, bo, bo, nullptr, nullptr, nullptr, out);
}